// Round 17
// baseline (107.936 us; speedup 1.0000x reference)
//
#include <hip/hip_runtime.h>
#include <hip/hip_bf16.h>

#define N_NODES 50000
#define N_GRAPHS 64
#define HID 100
#define HPB 112           // fp8 row stride in BYTES (7 chunks of 16)

#define BKE  4096         // edges per block in k_sort
#define NBIN 196          // buckets of 256 nodes: ceil(50000/256)
#define CAP  8192         // per-bucket segment capacity (mean 4096, sigma 64)
#define NPB 73            // nodes per gather block (73*7 = 511 of 512 threads)

// ---- workspace layout (float offsets) ----
// HS is fp8-e4m3 (scaled 2^6) [N][112] bytes
#define OFF_DINV 0
#define OFF_CNTF 50048
#define OFF_POOL 50112
#define OFF_WT1  50176                    // bf16 [112][128] = 7168 floats
#define OFF_HS   57344                    // fp8 [N][112] = 1.4M floats
#define OFF_ROWPTR 1457344                // N ints
#define OFF_DEG    1507392                // N ushorts (25088 floats)
#define OFF_EIDX   1532480                // ushort [NBIN*CAP] = 802816 floats
#define OFF_BE     2335296                // uint  [NBIN*CAP] = 1605632 floats
#define OFF_CURSOR 3940928                // NBIN ints (pad 256)
#define OFF_DONE   3941184                // 1 int (pad 64)
#define OFF_W2L    3941248                // 113 floats: w2l[0..111] (pad 0), [112]=b2.Wlin
#define OFF_Q      3941376                // N floats

typedef __attribute__((ext_vector_type(8))) short short8;
typedef __attribute__((ext_vector_type(4))) float floatx4;

__device__ inline unsigned short f2b(float f) {
    union { float f; unsigned int v; } x; x.f = f;
    unsigned int r = (x.v + 0x7fffu + ((x.v >> 16) & 1u)) >> 16;   // RTNE
    return (unsigned short)r;
}

// fp8 e4m3 codec, values pre-scaled by 2^6 (hs ~ N(0,0.4) -> normal-range codes).
// encode: b7 = RTNE(bits(|f|*2^-114) >> 20); robust whether f32 denorms flush or not
// (sub-2^-12 values contribute <= 3e-5 either way).
__device__ inline unsigned int f2e(float f) {
    float a = fabsf(f) * 0x1.0p-114f;
    a = fminf(a, 0x1.Cp-112f);                  // clamp at 448 (fp8 max)
    unsigned int u = __float_as_uint(a);
    unsigned int b = (u + 0x7FFFFu + ((u >> 20) & 1u)) >> 20;
    return b | ((__float_as_uint(f) >> 24) & 0x80u);
}
// decode: as_float(sign | (b&0x7f)<<20) * 2^114  (2^120 / 2^6 scale)
__device__ inline float e2f(unsigned int b) {
    return __uint_as_float(((b << 24) & 0x80000000u) | ((b & 0x7Fu) << 20)) * 0x1.0p114f;
}
__device__ inline void acc16(float* s, uint4 v) {
    unsigned int x;
    x = v.x; s[0]  += e2f(x); s[1]  += e2f(x >> 8); s[2]  += e2f(x >> 16); s[3]  += e2f(x >> 24);
    x = v.y; s[4]  += e2f(x); s[5]  += e2f(x >> 8); s[6]  += e2f(x >> 16); s[7]  += e2f(x >> 24);
    x = v.z; s[8]  += e2f(x); s[9]  += e2f(x >> 8); s[10] += e2f(x >> 16); s[11] += e2f(x >> 24);
    x = v.w; s[12] += e2f(x); s[13] += e2f(x >> 8); s[14] += e2f(x >> 16); s[15] += e2f(x >> 24);
}

// prep: blocks 0..55 transpose W1 -> Wt1; block 56: w2l + pool/cnt/done zero;
// block 57: zero bucket cursors.
__global__ __launch_bounds__(256) void k_prep(const float* __restrict__ W1,
                                              const float* __restrict__ W2,
                                              const float* __restrict__ Wlin,
                                              const float* __restrict__ b2,
                                              unsigned short* __restrict__ Wt1,
                                              float* __restrict__ w2l,
                                              float* __restrict__ pool,
                                              float* __restrict__ cntf,
                                              int* __restrict__ done,
                                              int* __restrict__ cursor) {
    const int b = blockIdx.x, t = threadIdx.x;
    if (b < 56) {
        int idx = b * 256 + t;
        int c = idx >> 7, k = idx & 127;
        float v = (k < 128 && c < HID) ? W1[k * HID + c] : 0.0f;
        Wt1[c * 128 + k] = f2b(v);
    } else if (b == 56) {
        if (t < 112) {
            float s = 0.0f;
            if (t < 100)
                for (int c = 0; c < HID; ++c) s += W2[t * HID + c] * Wlin[c];
            w2l[t] = s;
        } else if (t == 112) {
            float s = 0.0f;
            for (int j = 0; j < HID; ++j) s += b2[j] * Wlin[j];
            w2l[112] = s;
        } else if (t >= 128 && t < 128 + N_GRAPHS) {
            pool[t - 128] = 0.0f; cntf[t - 128] = 0.0f;
        } else if (t == 224) {
            *done = 0;
        }
    } else {
        if (t < NBIN) cursor[t] = 0;
    }
}

// k_sort: edges read ONCE; per-bucket slot reservation via atomicAdd on cursor.
__global__ __launch_bounds__(256) void k_sort(const int* __restrict__ src,
                                              const int* __restrict__ dst, int E,
                                              int* __restrict__ cursor,
                                              unsigned int* __restrict__ bE) {
    __shared__ unsigned int stage[BKE];
    __shared__ int hist[256], pref[256], cur[256], sb[256], resS[256];
    const int t = threadIdx.x, b = blockIdx.x;
    hist[t] = 0;
    __syncthreads();
    const int e0 = b * BKE, e1 = min(e0 + BKE, E), n = e1 - e0;
    unsigned int mine[16];
#pragma unroll
    for (int u = 0; u < 16; ++u) {
        int e = e0 + u * 256 + t;
        if (e < e1) {
            unsigned int v = ((unsigned int)src[e] << 16) | (unsigned int)dst[e];
            mine[u] = v;
            atomicAdd(&hist[(v >> 8) & 255], 1);
        }
    }
    __syncthreads();
    sb[t] = hist[t];
    __syncthreads();
    for (int off = 1; off < 256; off <<= 1) {
        int v = (t >= off) ? sb[t - off] : 0;
        __syncthreads();
        sb[t] += v;
        __syncthreads();
    }
    pref[t] = sb[t] - hist[t];
    cur[t] = pref[t];
    if (t < NBIN && hist[t] > 0) resS[t] = atomicAdd(&cursor[t], hist[t]);
    __syncthreads();
#pragma unroll
    for (int u = 0; u < 16; ++u) {
        int e = e0 + u * 256 + t;
        if (e < e1) {
            unsigned int v = mine[u];
            int p = atomicAdd(&cur[(v >> 8) & 255], 1);
            stage[p] = v;
        }
    }
    __syncthreads();
    for (int i = t; i < n; i += 256) {
        unsigned int v = stage[i];
        int bin = (v >> 8) & 255;
        int rel = resS[bin] + (i - pref[bin]);
        if (rel < CAP) bE[bin * CAP + rel] = v;
    }
}

// p4: per-bucket node sort -> rowptr, deg, dinv, eidx (segmented at b*CAP)
__global__ __launch_bounds__(256) void k_p4(const unsigned int* __restrict__ bE,
                                            const int* __restrict__ cursor,
                                            int* __restrict__ rowptr,
                                            unsigned short* __restrict__ deg,
                                            unsigned short* __restrict__ eidx,
                                            float* __restrict__ dinv) {
    __shared__ int hist[256], pref[256], cur[256], sb[256];
    const int t = threadIdx.x, b = blockIdx.x;
    const int eBase = b * CAP;
    int n = cursor[b];
    if (n > CAP) n = CAP;
    hist[t] = 0;
    __syncthreads();
    for (int i = t; i < n; i += 256) atomicAdd(&hist[bE[eBase + i] & 255], 1);
    __syncthreads();
    sb[t] = hist[t];
    __syncthreads();
    for (int off = 1; off < 256; off <<= 1) {
        int v = (t >= off) ? sb[t - off] : 0;
        __syncthreads();
        sb[t] += v;
        __syncthreads();
    }
    pref[t] = sb[t] - hist[t];
    cur[t] = pref[t];
    int node = (b << 8) + t;
    if (node < N_NODES) {
        rowptr[node] = eBase + pref[t];
        deg[node] = (unsigned short)hist[t];
        dinv[node] = rsqrtf((float)(hist[t] + 1));   // +1 self loop
    }
    __syncthreads();
    for (int i = t; i < n; i += 256) {
        unsigned int v = bE[eBase + i];
        int p = atomicAdd(&cur[v & 255], 1);
        eidx[eBase + p] = (unsigned short)(v >> 16);
    }
}

// MFMA bf16 GEMM (layer 1): hs[i][c] = fp8(dinv[i]*sum_k X[i][k]*W1[k][c]), [N][112B].
// Epilogue: deposit fp8 bytes into LDS (overlay on xs, sync-guarded), then
// coalesced uint4 row stores.
__global__ __launch_bounds__(256) void k_gemm(const float* __restrict__ A,   // [N][128] f32
                                              const unsigned short* __restrict__ Wt, // [112][128]
                                              const float* __restrict__ dinv,
                                              unsigned char* __restrict__ out) {
    __shared__ __align__(16) unsigned short xs[64][136];
    __shared__ __align__(16) unsigned short ws[112][136];
    const int t = threadIdx.x;
    const int base = blockIdx.x * 64;

    for (int idx = t; idx < 112 * 64; idx += 256) {
        int c = idx >> 6, u = idx & 63;
        *(unsigned int*)&ws[c][2 * u] = ((const unsigned int*)Wt)[idx];
    }
    for (int idx = t; idx < 64 * 32; idx += 256) {
        int r = idx >> 5, q = idx & 31;
        int row = base + r;
        ushort4 p;
        if (row < N_NODES) {
            float4 v = ((const float4*)(A + (size_t)row * 128))[q];
            p.x = f2b(v.x); p.y = f2b(v.y); p.z = f2b(v.z); p.w = f2b(v.w);
        } else p = make_ushort4(0, 0, 0, 0);
        *(ushort4*)&xs[r][4 * q] = p;
    }
    __syncthreads();

    const int lane = t & 63, w = t >> 6;
    const int g = lane >> 4, cl = lane & 15;

    floatx4 acc[7];
#pragma unroll
    for (int n = 0; n < 7; ++n) acc[n] = (floatx4){0.f, 0.f, 0.f, 0.f};

#pragma unroll
    for (int kc = 0; kc < 4; ++kc) {
        short8 a = *(const short8*)&xs[w * 16 + cl][kc * 32 + 8 * g];
#pragma unroll
        for (int n = 0; n < 7; ++n) {
            short8 b = *(const short8*)&ws[n * 16 + cl][kc * 32 + 8 * g];
            acc[n] = __builtin_amdgcn_mfma_f32_16x16x32_bf16(a, b, acc[n], 0, 0, 0);
        }
    }

    // epilogue: scale by dinv, encode fp8, deposit to LDS overlay, coalesced stores
    float di[4]; int lrows[4];
#pragma unroll
    for (int r = 0; r < 4; ++r) {
        lrows[r] = w * 16 + 4 * g + r;
        int grow = base + lrows[r];
        di[r] = (grow < N_NODES) ? dinv[grow] : 0.0f;
    }
    __syncthreads();                                   // all MFMA xs reads done
    unsigned char* os = (unsigned char*)&xs[0][0];     // [64][112] byte overlay
#pragma unroll
    for (int n = 0; n < 7; ++n) {
        int col = n * 16 + cl;
#pragma unroll
        for (int r = 0; r < 4; ++r)
            os[lrows[r] * HPB + col] = (unsigned char)f2e(acc[n][r] * di[r]);
    }
    __syncthreads();
    for (int idx = t; idx < 64 * 7; idx += 256) {
        int r = idx / 7, q = idx - r * 7;
        int row = base + r;
        if (row < N_NODES)
            *(uint4*)(out + (size_t)row * HPB + 16 * q) = *(const uint4*)(os + r * HPB + 16 * q);
    }
}

// Fused layer-1 gather + tanh + layer-2 matvec. Block = 512 thr = 73 nodes x 7 chunks.
// q[i] = dinv[i] * sum_j tanh(dinv[i]*(self+sum_src)[j] + b1[j]) * w2l[j]
// fp8 rows: 7 x 16B chunks (2 cache lines/row, was 4 at bf16). 8-deep edge unroll.
__global__ __launch_bounds__(512) void k_gather_q(const int* __restrict__ rowptr,
                                                  const unsigned short* __restrict__ deg,
                                                  const unsigned short* __restrict__ eidx,
                                                  const unsigned char* __restrict__ hs,
                                                  const float* __restrict__ dinv,
                                                  const float* __restrict__ b1,
                                                  const float* __restrict__ w2l,
                                                  float* __restrict__ q) {
    __shared__ float wl[112];
    __shared__ float bsh[112];
    __shared__ float part[512];
    const int t = threadIdx.x;
    if (t < 112) { wl[t] = w2l[t]; bsh[t] = (t < 100) ? b1[t] : 0.0f; }
    const int nid = t / 7, c = t - nid * 7;
    const int i = blockIdx.x * NPB + nid;
    const bool active = (t < NPB * 7) && (i < N_NODES);
    __syncthreads();

    float partial = 0.0f;
    float di = 0.0f;
    if (active) {
        const int c0 = 16 * c;
        float s[16];
#pragma unroll
        for (int j = 0; j < 16; ++j) s[j] = 0.0f;
        uint4 sv = *(const uint4*)(hs + (size_t)i * HPB + c0);   // self loop
        acc16(s, sv);
        int e = rowptr[i];
        const int end = e + deg[i];
        for (; e + 8 <= end; e += 8) {
            int n[8];
#pragma unroll
            for (int u = 0; u < 8; ++u) n[u] = eidx[e + u];
            uint4 v[8];
#pragma unroll
            for (int u = 0; u < 8; ++u) v[u] = *(const uint4*)(hs + (size_t)n[u] * HPB + c0);
#pragma unroll
            for (int u = 0; u < 8; ++u) acc16(s, v[u]);
        }
        for (; e + 4 <= end; e += 4) {
            int n[4];
#pragma unroll
            for (int u = 0; u < 4; ++u) n[u] = eidx[e + u];
            uint4 v[4];
#pragma unroll
            for (int u = 0; u < 4; ++u) v[u] = *(const uint4*)(hs + (size_t)n[u] * HPB + c0);
#pragma unroll
            for (int u = 0; u < 4; ++u) acc16(s, v[u]);
        }
        for (; e < end; ++e) {
            uint4 v = *(const uint4*)(hs + (size_t)eidx[e] * HPB + c0);
            acc16(s, v);
        }
        di = dinv[i];
#pragma unroll
        for (int j = 0; j < 16; ++j) {
            float h = tanhf(di * s[j] + bsh[c0 + j]);   // pad cols: s=0,b=0 -> h=0, wl=0
            partial += h * wl[c0 + j];
        }
    }
    part[t] = partial;
    __syncthreads();
    if (active && c == 0) {
        float sum = 0.0f;
#pragma unroll
        for (int j = 0; j < 7; ++j) sum += part[t + j];
        q[i] = di * sum;
    }
}

// fused layer-2 aggregate + mean-pool + final readout (last-block ticket)
__global__ __launch_bounds__(256) void k_gpool(const int* __restrict__ rowptr,
                                               const unsigned short* __restrict__ deg,
                                               const unsigned short* __restrict__ eidx,
                                               const float* __restrict__ q,
                                               const float* __restrict__ dinv,
                                               const int* __restrict__ batch,
                                               float* __restrict__ pool,
                                               float* __restrict__ cntf,
                                               const float* __restrict__ w2l,
                                               const float* __restrict__ blin,
                                               int* __restrict__ done,
                                               float* __restrict__ out) {
    __shared__ float sp[N_GRAPHS];
    __shared__ float sc[N_GRAPHS];
    __shared__ int lastFlag;
    const int t = threadIdx.x;
    if (t < N_GRAPHS) { sp[t] = 0.0f; sc[t] = 0.0f; }
    __syncthreads();
    int i = blockIdx.x * 256 + t;
    if (i < N_NODES) {
        float s = q[i];
        int e = rowptr[i];
        const int end = e + deg[i];
        for (; e + 8 <= end; e += 8) {
            int n0 = eidx[e],     n1 = eidx[e + 1], n2 = eidx[e + 2], n3 = eidx[e + 3];
            int n4 = eidx[e + 4], n5 = eidx[e + 5], n6 = eidx[e + 6], n7 = eidx[e + 7];
            s += q[n0] + q[n1] + q[n2] + q[n3] + q[n4] + q[n5] + q[n6] + q[n7];
        }
        for (; e + 4 <= end; e += 4) {
            int n0 = eidx[e], n1 = eidx[e + 1], n2 = eidx[e + 2], n3 = eidx[e + 3];
            s += q[n0] + q[n1] + q[n2] + q[n3];
        }
        for (; e < end; ++e) s += q[eidx[e]];
        float p = dinv[i] * s;
        int g = batch[i];
        atomicAdd(&sp[g], p);
        atomicAdd(&sc[g], 1.0f);
    }
    __syncthreads();
    if (t < N_GRAPHS && (sp[t] != 0.0f || sc[t] != 0.0f)) {
        atomicAdd(&pool[t], sp[t]);
        atomicAdd(&cntf[t], sc[t]);
    }
    __syncthreads();
    if (t == 0) {
        __threadfence();                                   // publish this block's adds
        int ticket = atomicAdd(done, 1);
        lastFlag = (ticket == (int)gridDim.x - 1);
    }
    __syncthreads();
    if (lastFlag && t < N_GRAPHS) {
        float p = atomicAdd(&pool[t], 0.0f);               // coherent read
        float c = atomicAdd(&cntf[t], 0.0f);
        out[t] = p / fmaxf(c, 1.0f) + w2l[112] + blin[0];
    }
}

extern "C" void kernel_launch(void* const* d_in, const int* in_sizes, int n_in,
                              void* d_out, int out_size, void* d_ws, size_t ws_size,
                              hipStream_t stream) {
    const float* x    = (const float*)d_in[0];
    const int*   ei   = (const int*)d_in[1];
    const int*   batch= (const int*)d_in[2];
    const float* W1   = (const float*)d_in[3];
    const float* b1   = (const float*)d_in[4];
    const float* W2   = (const float*)d_in[5];
    const float* b2   = (const float*)d_in[6];
    const float* Wlin = (const float*)d_in[7];
    const float* blin = (const float*)d_in[8];
    float* out = (float*)d_out;

    const int E = in_sizes[1] / 2;
    const int* src = ei;
    const int* dst = ei + E;

    float* wsf  = (float*)d_ws;
    int*   wsi  = (int*)d_ws;
    float* dinv = wsf + OFF_DINV;
    float* cntf = wsf + OFF_CNTF;
    float* pool = wsf + OFF_POOL;
    unsigned short* Wt1 = (unsigned short*)(wsf + OFF_WT1);
    unsigned char*  HS  = (unsigned char*)(wsf + OFF_HS);
    int* rowptr = wsi + OFF_ROWPTR;
    unsigned short* deg  = (unsigned short*)(wsi + OFF_DEG);
    unsigned short* eidx = (unsigned short*)(wsi + OFF_EIDX);
    unsigned int* bE = (unsigned int*)(wsi + OFF_BE);
    int* cursor = wsi + OFF_CURSOR;
    int* done   = wsi + OFF_DONE;
    float* w2l  = wsf + OFF_W2L;
    float* q    = wsf + OFF_Q;

    const int nbE = (E + BKE - 1) / BKE;            // 196 for E=800k
    const int nGrid = (N_NODES + 255) / 256;        // 196
    const int gqGrid = (N_NODES + NPB - 1) / NPB;   // 685

    // prep + single-pass bucket sort + per-bucket node sort
    k_prep<<<58, 256, 0, stream>>>(W1, W2, Wlin, b2, Wt1, w2l, pool, cntf, done, cursor);
    k_sort<<<nbE, 256, 0, stream>>>(src, dst, E, cursor, bE);
    k_p4<<<NBIN, 256, 0, stream>>>(bE, cursor, rowptr, deg, eidx, dinv);

    // layer 1 GEMM (fp8 output)
    k_gemm<<<(N_NODES + 63) / 64, 256, 0, stream>>>(x, Wt1, dinv, HS);

    // fused gather + tanh + layer-2 matvec -> q
    k_gather_q<<<gqGrid, 512, 0, stream>>>(rowptr, deg, eidx, HS, dinv, b1, w2l, q);

    // fused layer-2 aggregate + mean-pool + final readout
    k_gpool<<<nGrid, 256, 0, stream>>>(rowptr, deg, eidx, q, dinv, batch, pool, cntf,
                                       w2l, blin, done, out);
}

// Round 18
// 96.065 us; speedup vs baseline: 1.1236x; 1.1236x over previous
//
#include <hip/hip_runtime.h>
#include <hip/hip_bf16.h>

#define N_NODES 50000
#define N_GRAPHS 64
#define HID 100
#define HP 104            // padded bf16 row stride (13 * 8)

#define BKE  4096         // edges per block in k_sort
#define NBIN 196          // buckets of 256 nodes: ceil(50000/256)
#define CAP  8192         // per-bucket segment capacity (mean 4096, sigma 64)
#define NPB 39            // nodes per gather block (39*13 = 507 of 512 threads)

// ---- workspace layout (float offsets) ----
#define OFF_DINV 0
#define OFF_CNTF 50048
#define OFF_POOL 50112
#define OFF_WT1  50176                    // bf16 [112][128] = 7168 floats
#define OFF_HS   64512                    // bf16 [N][104] = 2.6M floats
#define OFF_ROWPTR 2664512                // N ints
#define OFF_DEG    2714560                // N ushorts (25088 floats)
#define OFF_EIDX   2739648                // ushort [NBIN*CAP] = 802816 floats
#define OFF_BE     3542464                // uint  [NBIN*CAP] = 1605632 floats
#define OFF_CURSOR 5148096                // NBIN ints (pad 256)
#define OFF_DONE   5148352                // 1 int (pad 64)
#define OFF_W2L    5148416                // 106 floats (pad 128)
#define OFF_Q      5148544                // N floats

typedef __attribute__((ext_vector_type(8))) short short8;
typedef __attribute__((ext_vector_type(4))) float floatx4;

__device__ inline float b2f(unsigned int u) {
    union { unsigned int v; float f; } x; x.v = u << 16; return x.f;
}
__device__ inline unsigned short f2b(float f) {
    union { float f; unsigned int v; } x; x.f = f;
    unsigned int r = (x.v + 0x7fffu + ((x.v >> 16) & 1u)) >> 16;   // RTNE
    return (unsigned short)r;
}

// prep: blocks 0..55 transpose W1 -> Wt1; block 56: w2l + pool/cnt/done zero;
// block 57: zero bucket cursors (must precede k_sort's reservations).
__global__ __launch_bounds__(256) void k_prep(const float* __restrict__ W1,
                                              const float* __restrict__ W2,
                                              const float* __restrict__ Wlin,
                                              const float* __restrict__ b2,
                                              unsigned short* __restrict__ Wt1,
                                              float* __restrict__ w2l,
                                              float* __restrict__ pool,
                                              float* __restrict__ cntf,
                                              int* __restrict__ done,
                                              int* __restrict__ cursor) {
    const int b = blockIdx.x, t = threadIdx.x;
    if (b < 56) {
        int idx = b * 256 + t;
        int c = idx >> 7, k = idx & 127;
        float v = (k < 128 && c < HID) ? W1[k * HID + c] : 0.0f;
        Wt1[c * 128 + k] = f2b(v);
    } else if (b == 56) {
        if (t < 104) {
            float s = 0.0f;
            if (t < 100)
                for (int c = 0; c < HID; ++c) s += W2[t * HID + c] * Wlin[c];
            w2l[t] = s;
        } else if (t == 104) {
            float s = 0.0f;
            for (int j = 0; j < HID; ++j) s += b2[j] * Wlin[j];
            w2l[104] = s;
        } else if (t >= 128 && t < 128 + N_GRAPHS) {
            pool[t - 128] = 0.0f; cntf[t - 128] = 0.0f;
        } else if (t == 224) {
            *done = 0;
        }
    } else {
        if (t < NBIN) cursor[t] = 0;
    }
}

// k_sort: edges read ONCE; per-bucket slot reservation via atomicAdd on cursor.
// Output: bE[bin*CAP + res .. ] packed (src<<16)|dst runs; cursor[bin] = count.
__global__ __launch_bounds__(256) void k_sort(const int* __restrict__ src,
                                              const int* __restrict__ dst, int E,
                                              int* __restrict__ cursor,
                                              unsigned int* __restrict__ bE) {
    __shared__ unsigned int stage[BKE];
    __shared__ int hist[256], pref[256], cur[256], sb[256], resS[256];
    const int t = threadIdx.x, b = blockIdx.x;
    hist[t] = 0;
    __syncthreads();
    const int e0 = b * BKE, e1 = min(e0 + BKE, E), n = e1 - e0;
    unsigned int mine[16];
#pragma unroll
    for (int u = 0; u < 16; ++u) {
        int e = e0 + u * 256 + t;
        if (e < e1) {
            unsigned int v = ((unsigned int)src[e] << 16) | (unsigned int)dst[e];
            mine[u] = v;
            atomicAdd(&hist[(v >> 8) & 255], 1);
        }
    }
    __syncthreads();
    sb[t] = hist[t];
    __syncthreads();
    for (int off = 1; off < 256; off <<= 1) {
        int v = (t >= off) ? sb[t - off] : 0;
        __syncthreads();
        sb[t] += v;
        __syncthreads();
    }
    pref[t] = sb[t] - hist[t];
    cur[t] = pref[t];
    if (t < NBIN && hist[t] > 0) resS[t] = atomicAdd(&cursor[t], hist[t]);
    __syncthreads();
#pragma unroll
    for (int u = 0; u < 16; ++u) {
        int e = e0 + u * 256 + t;
        if (e < e1) {
            unsigned int v = mine[u];
            int p = atomicAdd(&cur[(v >> 8) & 255], 1);
            stage[p] = v;
        }
    }
    __syncthreads();
    for (int i = t; i < n; i += 256) {
        unsigned int v = stage[i];
        int bin = (v >> 8) & 255;
        int rel = resS[bin] + (i - pref[bin]);
        if (rel < CAP) bE[bin * CAP + rel] = v;   // clamp (64-sigma margin; safety only)
    }
}

// p4: per-bucket node sort -> rowptr, deg, dinv, eidx (segmented at b*CAP)
__global__ __launch_bounds__(256) void k_p4(const unsigned int* __restrict__ bE,
                                            const int* __restrict__ cursor,
                                            int* __restrict__ rowptr,
                                            unsigned short* __restrict__ deg,
                                            unsigned short* __restrict__ eidx,
                                            float* __restrict__ dinv) {
    __shared__ int hist[256], pref[256], cur[256], sb[256];
    const int t = threadIdx.x, b = blockIdx.x;
    const int eBase = b * CAP;
    int n = cursor[b];
    if (n > CAP) n = CAP;
    hist[t] = 0;
    __syncthreads();
    for (int i = t; i < n; i += 256) atomicAdd(&hist[bE[eBase + i] & 255], 1);
    __syncthreads();
    sb[t] = hist[t];
    __syncthreads();
    for (int off = 1; off < 256; off <<= 1) {
        int v = (t >= off) ? sb[t - off] : 0;
        __syncthreads();
        sb[t] += v;
        __syncthreads();
    }
    pref[t] = sb[t] - hist[t];
    cur[t] = pref[t];
    int node = (b << 8) + t;
    if (node < N_NODES) {
        rowptr[node] = eBase + pref[t];
        deg[node] = (unsigned short)hist[t];
        dinv[node] = rsqrtf((float)(hist[t] + 1));   // +1 self loop
    }
    __syncthreads();
    for (int i = t; i < n; i += 256) {
        unsigned int v = bE[eBase + i];
        int p = atomicAdd(&cur[v & 255], 1);
        eidx[eBase + p] = (unsigned short)(v >> 16);
    }
}

// MFMA bf16 GEMM (layer 1): hs[i][c] = f2b(dinv[i]*sum_k X[i][k]*W1[k][c]), [N][HP] bf16.
// Epilogue via LDS transpose -> coalesced uint4 stores. Wave w reads AND writes only
// xs rows [16w,16w+16) so no sync needed before the in-place overwrite; one sync
// before the block-wide streamed store.
__global__ __launch_bounds__(256) void k_gemm(const float* __restrict__ A,   // [N][128] f32
                                              const unsigned short* __restrict__ Wt, // [112][128]
                                              const float* __restrict__ dinv,
                                              unsigned short* __restrict__ out) {
    __shared__ __align__(16) unsigned short xs[64][136];
    __shared__ __align__(16) unsigned short ws[112][136];
    const int t = threadIdx.x;
    const int base = blockIdx.x * 64;

    for (int idx = t; idx < 112 * 64; idx += 256) {
        int c = idx >> 6, u = idx & 63;
        *(unsigned int*)&ws[c][2 * u] = ((const unsigned int*)Wt)[idx];
    }
    for (int idx = t; idx < 64 * 32; idx += 256) {
        int r = idx >> 5, q = idx & 31;
        int row = base + r;
        ushort4 p;
        if (row < N_NODES) {
            float4 v = ((const float4*)(A + (size_t)row * 128))[q];
            p.x = f2b(v.x); p.y = f2b(v.y); p.z = f2b(v.z); p.w = f2b(v.w);
        } else p = make_ushort4(0, 0, 0, 0);
        *(ushort4*)&xs[r][4 * q] = p;
    }
    __syncthreads();

    const int lane = t & 63, w = t >> 6;
    const int g = lane >> 4, cl = lane & 15;

    floatx4 acc[7];
#pragma unroll
    for (int n = 0; n < 7; ++n) acc[n] = (floatx4){0.f, 0.f, 0.f, 0.f};

#pragma unroll
    for (int kc = 0; kc < 4; ++kc) {
        short8 a = *(const short8*)&xs[w * 16 + cl][kc * 32 + 8 * g];
#pragma unroll
        for (int n = 0; n < 7; ++n) {
            short8 b = *(const short8*)&ws[n * 16 + cl][kc * 32 + 8 * g];
            acc[n] = __builtin_amdgcn_mfma_f32_16x16x32_bf16(a, b, acc[n], 0, 0, 0);
        }
    }

    // epilogue: scale by dinv, deposit into own xs rows, then coalesced stores
    float di[4]; int lrows[4];
#pragma unroll
    for (int r = 0; r < 4; ++r) {
        lrows[r] = w * 16 + 4 * g + r;
        int grow = base + lrows[r];
        di[r] = (grow < N_NODES) ? dinv[grow] : 0.0f;
    }
#pragma unroll
    for (int n = 0; n < 7; ++n) {
        int col = n * 16 + cl;
#pragma unroll
        for (int r = 0; r < 4; ++r)
            xs[lrows[r]][col] = f2b(acc[n][r] * di[r]);
    }
    __syncthreads();
    for (int idx = t; idx < 64 * 13; idx += 256) {
        int r = idx / 13, q = idx - r * 13;
        int row = base + r;
        if (row < N_NODES)
            *(uint4*)(out + (size_t)row * HP + 8 * q) = *(const uint4*)&xs[r][8 * q];
    }
}

#define ACC8(v) do { \
    s[0] += b2f((v).x & 0xffff); s[1] += b2f((v).x >> 16); \
    s[2] += b2f((v).y & 0xffff); s[3] += b2f((v).y >> 16); \
    s[4] += b2f((v).z & 0xffff); s[5] += b2f((v).z >> 16); \
    s[6] += b2f((v).w & 0xffff); s[7] += b2f((v).w >> 16); } while (0)

// Fused layer-1 gather + tanh + layer-2 matvec. Block = 512 thr = 39 nodes x 13 chunks.
// q[i] = dinv[i] * sum_j tanh(dinv[i]*(self+sum_src)[j] + b1[j]) * w2l[j]
// end = rowptr[i] + deg[i] (segmented eidx). 16-deep edge unroll.
__global__ __launch_bounds__(512) void k_gather_q(const int* __restrict__ rowptr,
                                                  const unsigned short* __restrict__ deg,
                                                  const unsigned short* __restrict__ eidx,
                                                  const unsigned short* __restrict__ hs,
                                                  const float* __restrict__ dinv,
                                                  const float* __restrict__ b1,
                                                  const float* __restrict__ w2l,
                                                  float* __restrict__ q) {
    __shared__ float wl[104];
    __shared__ float bsh[104];
    __shared__ float part[512];
    const int t = threadIdx.x;
    if (t < 104) { wl[t] = w2l[t]; bsh[t] = (t < 100) ? b1[t] : 0.0f; }
    const int nid = t / 13, c = t - nid * 13;
    const int i = blockIdx.x * NPB + nid;
    const bool active = (t < NPB * 13) && (i < N_NODES);
    __syncthreads();

    float partial = 0.0f;
    float di = 0.0f;
    if (active) {
        const int c0 = 8 * c;
        float s[8] = {0.f, 0.f, 0.f, 0.f, 0.f, 0.f, 0.f, 0.f};
        uint4 sv = *(const uint4*)(hs + (size_t)i * HP + c0);   // self loop
        ACC8(sv);
        int e = rowptr[i];
        const int end = e + deg[i];
        for (; e + 16 <= end; e += 16) {
            int n[16];
#pragma unroll
            for (int u = 0; u < 16; ++u) n[u] = eidx[e + u];
            uint4 v[16];
#pragma unroll
            for (int u = 0; u < 16; ++u) v[u] = *(const uint4*)(hs + (size_t)n[u] * HP + c0);
#pragma unroll
            for (int u = 0; u < 16; ++u) ACC8(v[u]);
        }
        for (; e + 8 <= end; e += 8) {
            int n[8];
#pragma unroll
            for (int u = 0; u < 8; ++u) n[u] = eidx[e + u];
            uint4 v[8];
#pragma unroll
            for (int u = 0; u < 8; ++u) v[u] = *(const uint4*)(hs + (size_t)n[u] * HP + c0);
#pragma unroll
            for (int u = 0; u < 8; ++u) ACC8(v[u]);
        }
        for (; e + 4 <= end; e += 4) {
            int n[4];
#pragma unroll
            for (int u = 0; u < 4; ++u) n[u] = eidx[e + u];
            uint4 v[4];
#pragma unroll
            for (int u = 0; u < 4; ++u) v[u] = *(const uint4*)(hs + (size_t)n[u] * HP + c0);
#pragma unroll
            for (int u = 0; u < 4; ++u) ACC8(v[u]);
        }
        for (; e < end; ++e) {
            uint4 v = *(const uint4*)(hs + (size_t)eidx[e] * HP + c0);
            ACC8(v);
        }
        di = dinv[i];
#pragma unroll
        for (int j = 0; j < 8; ++j) {
            float h = tanhf(di * s[j] + bsh[c0 + j]);   // pad cols: s=0,b=0 -> h=0, wl=0
            partial += h * wl[c0 + j];
        }
    }
    part[t] = partial;
    __syncthreads();
    if (active && c == 0) {
        float sum = 0.0f;
#pragma unroll
        for (int j = 0; j < 13; ++j) sum += part[t + j];
        q[i] = di * sum;
    }
}

// fused layer-2 aggregate + mean-pool + final readout (last-block ticket)
__global__ __launch_bounds__(256) void k_gpool(const int* __restrict__ rowptr,
                                               const unsigned short* __restrict__ deg,
                                               const unsigned short* __restrict__ eidx,
                                               const float* __restrict__ q,
                                               const float* __restrict__ dinv,
                                               const int* __restrict__ batch,
                                               float* __restrict__ pool,
                                               float* __restrict__ cntf,
                                               const float* __restrict__ w2l,
                                               const float* __restrict__ blin,
                                               int* __restrict__ done,
                                               float* __restrict__ out) {
    __shared__ float sp[N_GRAPHS];
    __shared__ float sc[N_GRAPHS];
    __shared__ int lastFlag;
    const int t = threadIdx.x;
    if (t < N_GRAPHS) { sp[t] = 0.0f; sc[t] = 0.0f; }
    __syncthreads();
    int i = blockIdx.x * 256 + t;
    if (i < N_NODES) {
        float s = q[i];
        int e = rowptr[i];
        const int end = e + deg[i];
        for (; e + 8 <= end; e += 8) {
            int n0 = eidx[e],     n1 = eidx[e + 1], n2 = eidx[e + 2], n3 = eidx[e + 3];
            int n4 = eidx[e + 4], n5 = eidx[e + 5], n6 = eidx[e + 6], n7 = eidx[e + 7];
            s += q[n0] + q[n1] + q[n2] + q[n3] + q[n4] + q[n5] + q[n6] + q[n7];
        }
        for (; e + 4 <= end; e += 4) {
            int n0 = eidx[e], n1 = eidx[e + 1], n2 = eidx[e + 2], n3 = eidx[e + 3];
            s += q[n0] + q[n1] + q[n2] + q[n3];
        }
        for (; e < end; ++e) s += q[eidx[e]];
        float p = dinv[i] * s;
        int g = batch[i];
        atomicAdd(&sp[g], p);
        atomicAdd(&sc[g], 1.0f);
    }
    __syncthreads();
    if (t < N_GRAPHS && (sp[t] != 0.0f || sc[t] != 0.0f)) {
        atomicAdd(&pool[t], sp[t]);
        atomicAdd(&cntf[t], sc[t]);
    }
    __syncthreads();
    if (t == 0) {
        __threadfence();                                   // publish this block's adds
        int ticket = atomicAdd(done, 1);
        lastFlag = (ticket == (int)gridDim.x - 1);
    }
    __syncthreads();
    if (lastFlag && t < N_GRAPHS) {
        float p = atomicAdd(&pool[t], 0.0f);               // coherent read
        float c = atomicAdd(&cntf[t], 0.0f);
        out[t] = p / fmaxf(c, 1.0f) + w2l[104] + blin[0];
    }
}

extern "C" void kernel_launch(void* const* d_in, const int* in_sizes, int n_in,
                              void* d_out, int out_size, void* d_ws, size_t ws_size,
                              hipStream_t stream) {
    const float* x    = (const float*)d_in[0];
    const int*   ei   = (const int*)d_in[1];
    const int*   batch= (const int*)d_in[2];
    const float* W1   = (const float*)d_in[3];
    const float* b1   = (const float*)d_in[4];
    const float* W2   = (const float*)d_in[5];
    const float* b2   = (const float*)d_in[6];
    const float* Wlin = (const float*)d_in[7];
    const float* blin = (const float*)d_in[8];
    float* out = (float*)d_out;

    const int E = in_sizes[1] / 2;
    const int* src = ei;
    const int* dst = ei + E;

    float* wsf  = (float*)d_ws;
    int*   wsi  = (int*)d_ws;
    float* dinv = wsf + OFF_DINV;
    float* cntf = wsf + OFF_CNTF;
    float* pool = wsf + OFF_POOL;
    unsigned short* Wt1 = (unsigned short*)(wsf + OFF_WT1);
    unsigned short* HS  = (unsigned short*)(wsf + OFF_HS);
    int* rowptr = wsi + OFF_ROWPTR;
    unsigned short* deg  = (unsigned short*)(wsi + OFF_DEG);
    unsigned short* eidx = (unsigned short*)(wsi + OFF_EIDX);
    unsigned int* bE = (unsigned int*)(wsi + OFF_BE);
    int* cursor = wsi + OFF_CURSOR;
    int* done   = wsi + OFF_DONE;
    float* w2l  = wsf + OFF_W2L;
    float* q    = wsf + OFF_Q;

    const int nbE = (E + BKE - 1) / BKE;            // 196 for E=800k
    const int nGrid = (N_NODES + 255) / 256;        // 196
    const int gqGrid = (N_NODES + NPB - 1) / NPB;   // 1283

    // prep + single-pass bucket sort + per-bucket node sort
    k_prep<<<58, 256, 0, stream>>>(W1, W2, Wlin, b2, Wt1, w2l, pool, cntf, done, cursor);
    k_sort<<<nbE, 256, 0, stream>>>(src, dst, E, cursor, bE);
    k_p4<<<NBIN, 256, 0, stream>>>(bE, cursor, rowptr, deg, eidx, dinv);

    // layer 1 GEMM
    k_gemm<<<(N_NODES + 63) / 64, 256, 0, stream>>>(x, Wt1, dinv, HS);

    // fused gather + tanh + layer-2 matvec -> q
    k_gather_q<<<gqGrid, 512, 0, stream>>>(rowptr, deg, eidx, HS, dinv, b1, w2l, q);

    // fused layer-2 aggregate + mean-pool + final readout
    k_gpool<<<nGrid, 256, 0, stream>>>(rowptr, deg, eidx, q, dinv, batch, pool, cntf,
                                       w2l, blin, done, out);
}